// Round 8
// baseline (351.904 us; speedup 1.0000x reference)
//
#include <hip/hip_runtime.h>
#include <math.h>

#define H 51
#define TSEEN 256
#define FUT 16
#define TTOT (TSEEN + FUT)
#define NB 8
#define THREADS 512
#define NBLOCKS (2048 / NB)   // 256 blocks -> 1/CU, 8 waves (4 X + 4 Y)

typedef _Float16 f16;
typedef _Float16 f16x8 __attribute__((ext_vector_type(8)));
typedef float f32x4 __attribute__((ext_vector_type(4)));

__device__ __forceinline__ float fast_rcp(float x) { return __builtin_amdgcn_rcpf(x); }
__device__ __forceinline__ float sigf(float x) { return fast_rcp(1.f + __expf(-x)); }
__device__ __forceinline__ float tanhf_(float x) {
  return fmaf(2.f, fast_rcp(1.f + __expf(-2.f * x)), -1.f);
}
__device__ __forceinline__ void cellup(const f32x4& g, float& c, float& h) {
  float iv = sigf(g[0]), fv = sigf(g[1]);
  float gv = tanhf_(g[2]), ov = sigf(g[3]);
  c = fmaf(fv, c, iv * gv);
  h = ov * tanhf_(c);
}

#define MFMA __builtin_amdgcn_mfma_f32_16x16x32_f16

__launch_bounds__(THREADS, 2)
__global__ void lstm2_kernel(const float* __restrict__ inp,
                             const float* __restrict__ Wih1,
                             const float* __restrict__ bih1,
                             const float* __restrict__ Whh1,
                             const float* __restrict__ bhh1,
                             const float* __restrict__ Wih2,
                             const float* __restrict__ bih2,
                             const float* __restrict__ Whh2,
                             const float* __restrict__ bhh2,
                             const float* __restrict__ Wlin,
                             const float* __restrict__ blin,
                             float* __restrict__ out)
{
  // Single-parity B-operand frag buffers: [hi/lo][ktile][lane][j]
  // logical (k,n): lane = n + 16*((k&31)>>3), j = k&7
  // Bh1 written only in alpha (X), read only in beta (X:G1, Y:G2ih).
  // Bh2 written only in beta (Y),  read only in alpha (Y:G2hh).
  __shared__ __align__(16) f16 Bh1[2][2][64][8];
  __shared__ __align__(16) f16 Bh2[2][2][64][8];
  __shared__ __align__(16) float xs[TSEEN][NB];
  __shared__ float parts[4][NB];   // written beta (Y), read alpha/fb (X)

  const int tid  = threadIdx.x;
  const int wv   = tid >> 6;
  const int lane = tid & 63;
  const int l15  = lane & 15;
  const int g4   = lane >> 4;
  const int bq   = l15 & 7;
  const bool hi8 = (l15 & 8) != 0;
  const int baseb = blockIdx.x * NB;
  const bool isX = (wv < 4);
  const int w4   = isX ? wv : (wv - 4);
  const f32x4 zf = {0.f, 0.f, 0.f, 0.f};

  // ---- zero frag buffers (pad slots stay 0 forever) ----
  {
    f16* b1 = &Bh1[0][0][0][0];
    f16* b2 = &Bh2[0][0][0][0];
    for (int i = tid; i < 2 * 2 * 64 * 8; i += THREADS) {
      b1[i] = (f16)0.f; b2[i] = (f16)0.f;
    }
  }
  // ---- stage inputs ----
  for (int i = tid; i < NB * TSEEN; i += THREADS) {
    int b = i >> 8, t = i & 255;
    xs[t][b] = inp[(size_t)(baseb + b) * TSEEN + t];
  }
  if (tid < 4 * NB) (&parts[0][0])[tid] = 0.f;

  // ---- this lane's two cells (after xor-8 exchange) ----
  // tiles owned by wave: T_m = w4 + 4m; acc[m] unit = 4*T_m + g4, batch = l15
  // cellA = acc[2*hi8], cellB = acc[2*hi8+1] (partner's via xor-8), batch bq
  const int uA = 4 * w4 + (hi8 ? 32 : 0) + g4;   // always < 48 -> valid
  const int uB = uA + 16;                         // < 64, valid iff < 51
  const bool vB = (uB < H);
  const float bl = blin[0];

  __syncthreads();
  // x(0) into Bh1 k-slot 51 (kt=1, lane n+32, j=3)
  if (tid < NB) {
    float x0 = xs[0][tid];
    f16 xh = (f16)x0;
    Bh1[0][1][tid + 32][3] = xh;
    Bh1[1][1][tid + 32][3] = (f16)(x0 - (float)xh);
  }
  __syncthreads();

  if (isX) {
    // ================= role X: layer 1 =================
    f16x8 A1[4][2];
    f32x4 bias1[4];
    #pragma unroll
    for (int m = 0; m < 4; ++m) {
      const int T = w4 + 4 * m;
      const int uR = 4 * T + (l15 >> 2);
      const int gR = l15 & 3;
      const bool vR = (uR < H);
      const int row = gR * H + (vR ? uR : 0);
      #pragma unroll
      for (int kt = 0; kt < 2; ++kt)
        #pragma unroll
        for (int j = 0; j < 8; ++j) {
          const int k = 32 * kt + 8 * g4 + j;
          float w = 0.f;
          if (vR) {
            if (k < H) w = Whh1[row * H + k];
            else if (k == H) w = Wih1[row];   // x folded at k=51
          }
          A1[m][kt][j] = (f16)w;
        }
      const int uc = 4 * T + g4;
      const bool vc = (uc < H);
      #pragma unroll
      for (int r = 0; r < 4; ++r) {
        const int rr = r * H + (vc ? uc : 0);
        bias1[m][r] = vc ? (bih1[rr] + bhh1[rr]) : 0.f;
      }
    }

    float c1A = 0.f, c1B = 0.f;
    f32x4 acc[4];

    auto runG1 = [&]() {
      const f16x8 h0  = *(const f16x8*)&Bh1[0][0][lane][0];
      const f16x8 h1v = *(const f16x8*)&Bh1[0][1][lane][0];
      const f16x8 l0  = *(const f16x8*)&Bh1[1][0][lane][0];
      const f16x8 l1  = *(const f16x8*)&Bh1[1][1][lane][0];
      __builtin_amdgcn_s_setprio(1);
      #pragma unroll
      for (int m = 0; m < 4; ++m) {
        f32x4 hc = MFMA(A1[m][0], h0, bias1[m], 0, 0, 0);
        hc = MFMA(A1[m][1], h1v, hc, 0, 0, 0);
        f32x4 lc = MFMA(A1[m][0], l0, zf, 0, 0, 0);
        lc = MFMA(A1[m][1], l1, lc, 0, 0, 0);
        acc[m] = hc + lc;
      }
      __builtin_amdgcn_s_setprio(0);
    };

    runG1();   // prologue: G1(0) from zeroed h1 + x(0)

    #pragma unroll 1
    for (int t = 0; t < TTOT; ++t) {
      // -------- alpha: C1(t) --------
      f32x4 gA, gB;
      {
        f32x4 e2, e3;
        #pragma unroll
        for (int r = 0; r < 4; ++r) {
          e2[r] = __shfl_xor(acc[2][r], 8, 64);
          e3[r] = __shfl_xor(acc[3][r], 8, 64);
        }
        gA = hi8 ? e2 : acc[0];
        gB = hi8 ? e3 : acc[1];
      }
      float h1A, h1B;
      cellup(gA, c1A, h1A);
      cellup(gB, c1B, h1B);
      {
        f16 ha = (f16)h1A;
        Bh1[0][uA >> 5][bq + 16 * ((uA >> 3) & 3)][uA & 7] = ha;
        Bh1[1][uA >> 5][bq + 16 * ((uA >> 3) & 3)][uA & 7] = (f16)(h1A - (float)ha);
        if (vB) {
          f16 hb = (f16)h1B;
          Bh1[0][uB >> 5][bq + 16 * ((uB >> 3) & 3)][uB & 7] = hb;
          Bh1[1][uB >> 5][bq + 16 * ((uB >> 3) & 3)][uB & 7] = (f16)(h1B - (float)hb);
        }
      }
      if (t + 1 < TSEEN && tid < NB) {   // stage x(t+1)
        float xn = xs[t + 1][tid];
        f16 xh = (f16)xn;
        Bh1[0][1][tid + 32][3] = xh;
        Bh1[1][1][tid + 32][3] = (f16)(xn - (float)xh);
      }
      if (t >= 1 && t <= TSEEN - 1 && tid < NB) {   // out(t-1), t-1 in [0,254]
        float s = parts[0][tid] + parts[1][tid] + parts[2][tid] + parts[3][tid] + bl;
        out[(size_t)(baseb + tid) * TTOT + (t - 1)] = s;
      }
      __syncthreads();   // A

      // -------- beta: G1(t+1) (seen steps) --------
      if (t < TSEEN - 1) runG1();
      __syncthreads();   // B

      // -------- feedback turnaround (t >= 255) --------
      if (t >= TSEEN - 1) {
        if (tid < NB) {
          float fbv = parts[0][tid] + parts[1][tid] + parts[2][tid] + parts[3][tid] + bl;
          out[(size_t)(baseb + tid) * TTOT + t] = fbv;
          if (t < TTOT - 1) {
            f16 xh = (f16)fbv;
            Bh1[0][1][tid + 32][3] = xh;
            Bh1[1][1][tid + 32][3] = (f16)(fbv - (float)xh);
          }
        }
        __syncthreads();   // C
        if (t < TTOT - 1) runG1();
        __syncthreads();   // D
      }
    }
  } else {
    // ================= role Y: layer 2 =================
    f16x8 A3[4][2], A2f[4][2];
    f32x4 bias2[4];
    #pragma unroll
    for (int m = 0; m < 4; ++m) {
      const int T = w4 + 4 * m;
      const int uR = 4 * T + (l15 >> 2);
      const int gR = l15 & 3;
      const bool vR = (uR < H);
      const int row = gR * H + (vR ? uR : 0);
      #pragma unroll
      for (int kt = 0; kt < 2; ++kt)
        #pragma unroll
        for (int j = 0; j < 8; ++j) {
          const int k = 32 * kt + 8 * g4 + j;
          float w3 = 0.f, w2 = 0.f;
          if (vR && k < H) {
            w3 = Whh2[row * H + k];
            w2 = Wih2[row * H + k];
          }
          A3[m][kt][j]  = (f16)w3;
          A2f[m][kt][j] = (f16)w2;
        }
      const int uc = 4 * T + g4;
      const bool vc = (uc < H);
      #pragma unroll
      for (int r = 0; r < 4; ++r) {
        const int rr = r * H + (vc ? uc : 0);
        bias2[m][r] = vc ? (bih2[rr] + bhh2[rr]) : 0.f;
      }
    }
    const float wlA = Wlin[uA];
    const float wlB = vB ? Wlin[uB] : 0.f;

    float c2A = 0.f, c2B = 0.f;
    f32x4 hAcc[4], lAcc[4];

    #pragma unroll 1
    for (int t = 0; t < TTOT; ++t) {
      // -------- alpha: G2hh(t) = A3 . h2(t-1), acc kept in regs --------
      {
        const f16x8 h0  = *(const f16x8*)&Bh2[0][0][lane][0];
        const f16x8 h1v = *(const f16x8*)&Bh2[0][1][lane][0];
        const f16x8 l0  = *(const f16x8*)&Bh2[1][0][lane][0];
        const f16x8 l1  = *(const f16x8*)&Bh2[1][1][lane][0];
        __builtin_amdgcn_s_setprio(1);
        #pragma unroll
        for (int m = 0; m < 4; ++m) {
          hAcc[m] = MFMA(A3[m][0], h0, bias2[m], 0, 0, 0);
          hAcc[m] = MFMA(A3[m][1], h1v, hAcc[m], 0, 0, 0);
          lAcc[m] = MFMA(A3[m][0], l0, zf, 0, 0, 0);
          lAcc[m] = MFMA(A3[m][1], l1, lAcc[m], 0, 0, 0);
        }
        __builtin_amdgcn_s_setprio(0);
      }
      __syncthreads();   // A

      // -------- beta: G2ih(t) += A2 . h1(t); C2(t); head --------
      {
        const f16x8 h0  = *(const f16x8*)&Bh1[0][0][lane][0];
        const f16x8 h1v = *(const f16x8*)&Bh1[0][1][lane][0];
        const f16x8 l0  = *(const f16x8*)&Bh1[1][0][lane][0];
        const f16x8 l1  = *(const f16x8*)&Bh1[1][1][lane][0];
        __builtin_amdgcn_s_setprio(1);
        f32x4 acc[4];
        #pragma unroll
        for (int m = 0; m < 4; ++m) {
          hAcc[m] = MFMA(A2f[m][0], h0, hAcc[m], 0, 0, 0);
          hAcc[m] = MFMA(A2f[m][1], h1v, hAcc[m], 0, 0, 0);
          lAcc[m] = MFMA(A2f[m][0], l0, lAcc[m], 0, 0, 0);
          lAcc[m] = MFMA(A2f[m][1], l1, lAcc[m], 0, 0, 0);
          acc[m] = hAcc[m] + lAcc[m];
        }
        __builtin_amdgcn_s_setprio(0);

        f32x4 gA, gB;
        {
          f32x4 e2, e3;
          #pragma unroll
          for (int r = 0; r < 4; ++r) {
            e2[r] = __shfl_xor(acc[2][r], 8, 64);
            e3[r] = __shfl_xor(acc[3][r], 8, 64);
          }
          gA = hi8 ? e2 : acc[0];
          gB = hi8 ? e3 : acc[1];
        }
        float h2A, h2B;
        cellup(gA, c2A, h2A);
        cellup(gB, c2B, h2B);
        {
          f16 ha = (f16)h2A;
          Bh2[0][uA >> 5][bq + 16 * ((uA >> 3) & 3)][uA & 7] = ha;
          Bh2[1][uA >> 5][bq + 16 * ((uA >> 3) & 3)][uA & 7] = (f16)(h2A - (float)ha);
          if (vB) {
            f16 hb = (f16)h2B;
            Bh2[0][uB >> 5][bq + 16 * ((uB >> 3) & 3)][uB & 7] = hb;
            Bh2[1][uB >> 5][bq + 16 * ((uB >> 3) & 3)][uB & 7] = (f16)(h2B - (float)hb);
          }
        }
        float pv = fmaf(wlA, h2A, wlB * h2B);
        pv += __shfl_xor(pv, 8, 64);
        pv += __shfl_xor(pv, 16, 64);
        pv += __shfl_xor(pv, 32, 64);
        if (lane < NB) parts[w4][lane] = pv;
      }
      __syncthreads();   // B

      if (t >= TSEEN - 1) {   // keep barrier sequence symmetric with X
        __syncthreads();   // C
        __syncthreads();   // D
      }
    }
  }
}

extern "C" void kernel_launch(void* const* d_in, const int* in_sizes, int n_in,
                              void* d_out, int out_size, void* d_ws, size_t ws_size,
                              hipStream_t stream) {
  (void)in_sizes; (void)n_in; (void)d_ws; (void)ws_size; (void)out_size;
  const float* inp  = (const float*)d_in[0];
  const float* Wih1 = (const float*)d_in[1];
  const float* bih1 = (const float*)d_in[2];
  const float* Whh1 = (const float*)d_in[3];
  const float* bhh1 = (const float*)d_in[4];
  const float* Wih2 = (const float*)d_in[5];
  const float* bih2 = (const float*)d_in[6];
  const float* Whh2 = (const float*)d_in[7];
  const float* bhh2 = (const float*)d_in[8];
  const float* Wlin = (const float*)d_in[9];
  const float* blin = (const float*)d_in[10];
  float* outp = (float*)d_out;

  lstm2_kernel<<<NBLOCKS, THREADS, 0, stream>>>(
      inp, Wih1, bih1, Whh1, bhh1, Wih2, bih2, Whh2, bhh2, Wlin, blin, outp);
}

// Round 9
// 288.555 us; speedup vs baseline: 1.2195x; 1.2195x over previous
//
#include <hip/hip_runtime.h>
#include <math.h>

#define H 51
#define TSEEN 256
#define FUT 16
#define TTOT (TSEEN + FUT)
#define NB 8
#define THREADS 512
#define NWAVE 8
#define UPW 7                 // units per wave (8*7=56 >= 51)
#define NBLOCKS (2048 / NB)   // 256 blocks -> 1/CU, 8 waves = 2 waves/SIMD

typedef _Float16 f16;
typedef _Float16 f16x8 __attribute__((ext_vector_type(8)));
typedef float f32x4 __attribute__((ext_vector_type(4)));

__device__ __forceinline__ float fast_rcp(float x) { return __builtin_amdgcn_rcpf(x); }
// sigmoid/tanh via v_exp; both saturate cleanly (rcp(inf)=0)
__device__ __forceinline__ float sigf(float x) {
  return fast_rcp(1.f + __expf(-x));
}
__device__ __forceinline__ float tanhf_(float x) {
  return fmaf(2.f, fast_rcp(1.f + __expf(-2.f * x)), -1.f);
}

// lane^8 within each 16-lane row: DPP row_ror:8 (VALU pipe, not LDS!)
__device__ __forceinline__ float xor8f(float v) {
  return __int_as_float(__builtin_amdgcn_mov_dpp(__float_as_int(v), 0x128, 0xf, 0xf, true));
}

#define MFMA __builtin_amdgcn_mfma_f32_16x16x32_f16

__launch_bounds__(THREADS, 2)
__global__ void lstm2_kernel(const float* __restrict__ inp,
                             const float* __restrict__ Wih1,
                             const float* __restrict__ bih1,
                             const float* __restrict__ Whh1,
                             const float* __restrict__ bhh1,
                             const float* __restrict__ Wih2,
                             const float* __restrict__ bih2,
                             const float* __restrict__ Whh2,
                             const float* __restrict__ bhh2,
                             const float* __restrict__ Wlin,
                             const float* __restrict__ blin,
                             float* __restrict__ out)
{
  // B-operand buffers in MFMA fragment layout:
  // [parity][hi/lo][ktile][lane][j]; logical (k,n): lane = n + 16*((k&31)>>3), j = k&7
  __shared__ __align__(16) f16 Bh1[2][2][2][64][8];
  __shared__ __align__(16) f16 Bh2[2][2][2][64][8];
  __shared__ __align__(16) float xs[TSEEN][NB];
  __shared__ float parts[2][NWAVE][NB];
  __shared__ float outb[TTOT][NB];   // staged outputs; flushed once at the end

  const int tid  = threadIdx.x;
  const int wv   = tid >> 6;
  const int lane = tid & 63;
  const int l15  = lane & 15;
  const int g4   = lane >> 4;
  const int bq   = l15 & 7;            // this lane's batch for the cell phase
  const bool mhi = (l15 & 8) != 0;     // takes the m=1 accumulator via xor-8
  const int baseb = blockIdx.x * NB;

  // ---- zero B buffers (pad slots stay 0 forever) ----
  {
    f16* b1 = &Bh1[0][0][0][0][0];
    f16* b2 = &Bh2[0][0][0][0][0];
    for (int i = tid; i < 2 * 2 * 2 * 64 * 8; i += THREADS) {
      b1[i] = (f16)0.f; b2[i] = (f16)0.f;
    }
  }
  // ---- stage inputs (coalesced per batch row) ----
  for (int i = tid; i < NB * TSEEN; i += THREADS) {
    int b = i >> 8, t = i & 255;
    xs[t][b] = inp[(size_t)(baseb + b) * TSEEN + t];
  }
  if (tid < 2 * NWAVE * NB) (&parts[0][0][0])[tid] = 0.f;

  // ---- A fragments (f16), virtual row v = 4*unit_slot + gate; 2 M-tiles/wave ----
  f16x8 A1[2][2], A2[2][2], A3[2][2];
  #pragma unroll
  for (int m = 0; m < 2; ++m) {
    const int slotA = 4 * m + (l15 >> 2);
    const int uA = UPW * wv + slotA;
    const int gA = l15 & 3;
    const bool vA = (slotA < UPW) && (uA < H);
    const int row = gA * H + (vA ? uA : 0);
    #pragma unroll
    for (int kt = 0; kt < 2; ++kt) {
      #pragma unroll
      for (int j = 0; j < 8; ++j) {
        const int k = 32 * kt + 8 * g4 + j;
        float w1 = 0.f, w2 = 0.f, w3 = 0.f;
        if (vA) {
          if (k < H) {
            w1 = Whh1[row * H + k];
            w2 = Wih2[row * H + k];
            w3 = Whh2[row * H + k];
          } else if (k == H) {
            w1 = Wih1[row];        // x folded in as k-slot 51 (layer 1 only)
          }
        }
        A1[m][kt][j] = (f16)w1;
        A2[m][kt][j] = (f16)w2;
        A3[m][kt][j] = (f16)w3;
      }
    }
  }

  // ---- bias C-in fragments (C layout: unit_slot = 4m+g4, gate = reg) ----
  f32x4 bias1[2], bias2[2];
  #pragma unroll
  for (int m = 0; m < 2; ++m) {
    const int ulC = 4 * m + g4;
    const int u = UPW * wv + ulC;
    const bool v = (ulC < UPW) && (u < H);
    #pragma unroll
    for (int r = 0; r < 4; ++r) {
      const int rr = r * H + (v ? u : 0);
      bias1[m][r] = v ? (bih1[rr] + bhh1[rr]) : 0.f;
      bias2[m][r] = v ? (bih2[rr] + bhh2[rr]) : 0.f;
    }
  }

  // ---- this lane's cell: unit slot (mhi? 4:0)+g4, batch bq ----
  const int slotC = (mhi ? 4 : 0) + g4;
  const int uC0 = UPW * wv + slotC;
  const bool vC = (slotC < UPW) && (uC0 < H);
  const int uC = vC ? uC0 : 0;
  const float wl = vC ? Wlin[uC] : 0.f;
  const float bl = blin[0];
  const int wkt = uC >> 5;                    // h-frag write address for (uC,bq)
  const int wln = bq + 16 * ((uC >> 3) & 3);
  const int wj  = uC & 7;

  float c1 = 0.f, c2 = 0.f;
  const f32x4 zf = {0.f, 0.f, 0.f, 0.f};

  __syncthreads();
  // x(0) into stale-parity h1 buffer, k-slot 51 (kt=1 -> lane n+32, j=3)
  if (tid < NB) {
    float x0 = xs[0][tid];
    f16 xh = (f16)x0;
    Bh1[1][0][1][tid + 32][3] = xh;
    Bh1[1][1][1][tid + 32][3] = (f16)(x0 - (float)xh);
  }
  __syncthreads();

  #pragma unroll 1
  for (int t = 0; t < TTOT; ++t) {
    const int pw = t & 1, pr = pw ^ 1;

    // ============ phase 1: layer 1 only (reads Bh1[pr], incl. x at k=51) ============
    const f16x8 b1h0 = *(const f16x8*)&Bh1[pr][0][0][lane][0];
    const f16x8 b1h1 = *(const f16x8*)&Bh1[pr][0][1][lane][0];
    const f16x8 b1l0 = *(const f16x8*)&Bh1[pr][1][0][lane][0];
    const f16x8 b1l1 = *(const f16x8*)&Bh1[pr][1][1][lane][0];

    f32x4 ac1[2];
    #pragma unroll
    for (int m = 0; m < 2; ++m) {
      f32x4 hiC = MFMA(A1[m][0], b1h0, bias1[m], 0, 0, 0);
      hiC = MFMA(A1[m][1], b1h1, hiC, 0, 0, 0);
      f32x4 loC = MFMA(A1[m][0], b1l0, zf, 0, 0, 0);
      loC = MFMA(A1[m][1], b1l1, loC, 0, 0, 0);
      ac1[m] = hiC + loC;
    }

    // xor-8 exchange via DPP (VALU) -> 1 cell per lane
    float q0, q1, q2, q3;
    {
      float e0 = xor8f(ac1[1][0]);
      float e1 = xor8f(ac1[1][1]);
      float e2 = xor8f(ac1[1][2]);
      float e3 = xor8f(ac1[1][3]);
      q0 = mhi ? e0 : ac1[0][0];
      q1 = mhi ? e1 : ac1[0][1];
      q2 = mhi ? e2 : ac1[0][2];
      q3 = mhi ? e3 : ac1[0][3];
    }
    {
      float iv = sigf(q0), fv = sigf(q1);
      float gv = tanhf_(q2), ov = sigf(q3);
      c1 = fmaf(fv, c1, iv * gv);
      float h1n = ov * tanhf_(c1);
      if (vC) {
        f16 hh = (f16)h1n;
        Bh1[pw][0][wkt][wln][wj] = hh;
        Bh1[pw][1][wkt][wln][wj] = (f16)(h1n - (float)hh);
      }
    }
    // x(t+1) from input, written pre-barrier (slot 51 disjoint from h-slots;
    // phase-2 reads of slot 51 hit a zero column in A2)
    if (t + 1 < TSEEN && tid < NB) {
      float xn = xs[t + 1][tid];
      f16 xh = (f16)xn;
      Bh1[pw][0][1][tid + 32][3] = xh;
      Bh1[pw][1][1][tid + 32][3] = (f16)(xn - (float)xh);
    }
    __syncthreads();   // barrier A — the only per-step barrier (seen phase)

    // deferred output: out(t-1) for t-1 in [0, 254] -> LDS stage (no global store)
    if (t >= 1 && t < TSEEN && tid < NB) {
      float s = bl;
      #pragma unroll
      for (int w = 0; w < NWAVE; ++w) s += parts[pr][w][tid];
      outb[t - 1][tid] = s;
    }

    // ============ phase 2: layer 2 (hh from Bh2[pr], ih from fresh Bh1[pw]) ============
    const f16x8 b2h0 = *(const f16x8*)&Bh2[pr][0][0][lane][0];
    const f16x8 b2h1 = *(const f16x8*)&Bh2[pr][0][1][lane][0];
    const f16x8 b2l0 = *(const f16x8*)&Bh2[pr][1][0][lane][0];
    const f16x8 b2l1 = *(const f16x8*)&Bh2[pr][1][1][lane][0];
    const f16x8 f1h0 = *(const f16x8*)&Bh1[pw][0][0][lane][0];
    const f16x8 f1h1 = *(const f16x8*)&Bh1[pw][0][1][lane][0];
    const f16x8 f1l0 = *(const f16x8*)&Bh1[pw][1][0][lane][0];
    const f16x8 f1l1 = *(const f16x8*)&Bh1[pw][1][1][lane][0];

    f32x4 ac2[2];
    #pragma unroll
    for (int m = 0; m < 2; ++m) {
      f32x4 rA = MFMA(A3[m][0], b2h0, bias2[m], 0, 0, 0);
      rA = MFMA(A3[m][1], b2h1, rA, 0, 0, 0);
      f32x4 rB = MFMA(A3[m][0], b2l0, zf, 0, 0, 0);
      rB = MFMA(A3[m][1], b2l1, rB, 0, 0, 0);
      f32x4 rC = MFMA(A2[m][0], f1h0, zf, 0, 0, 0);
      rC = MFMA(A2[m][1], f1h1, rC, 0, 0, 0);
      f32x4 rD = MFMA(A2[m][0], f1l0, zf, 0, 0, 0);
      rD = MFMA(A2[m][1], f1l1, rD, 0, 0, 0);
      ac2[m] = (rA + rB) + (rC + rD);
    }

    // exchange (DPP) + cell + head
    {
      float e0 = xor8f(ac2[1][0]);
      float e1 = xor8f(ac2[1][1]);
      float e2 = xor8f(ac2[1][2]);
      float e3 = xor8f(ac2[1][3]);
      q0 = mhi ? e0 : ac2[0][0];
      q1 = mhi ? e1 : ac2[0][1];
      q2 = mhi ? e2 : ac2[0][2];
      q3 = mhi ? e3 : ac2[0][3];
    }
    float pv;
    {
      float iv = sigf(q0), fv = sigf(q1);
      float gv = tanhf_(q2), ov = sigf(q3);
      c2 = fmaf(fv, c2, iv * gv);
      float h2n = ov * tanhf_(c2);
      pv = wl * h2n;
      if (vC) {
        f16 hh = (f16)h2n;
        Bh2[pw][0][wkt][wln][wj] = hh;
        Bh2[pw][1][wkt][wln][wj] = (f16)(h2n - (float)hh);
      }
    }
    // butterfly over unit slots: xor8 via DPP (VALU), xor16/32 via bpermute
    pv += xor8f(pv);
    pv += __shfl_xor(pv, 16, 64);
    pv += __shfl_xor(pv, 32, 64);
    if (lane < NB) parts[pw][wv][lane] = pv;

    // feedback phase: x(t+1) = out(t); also emit outs 255..271
    if (t >= TSEEN - 1) {
      __syncthreads();   // publish parts[pw]
      if (tid < NB) {
        float fbv = bl;
        #pragma unroll
        for (int w = 0; w < NWAVE; ++w) fbv += parts[pw][w][tid];
        outb[t][tid] = fbv;
        if (t < TTOT - 1) {
          f16 xh = (f16)fbv;
          Bh1[pw][0][1][tid + 32][3] = xh;
          Bh1[pw][1][1][tid + 32][3] = (f16)(fbv - (float)xh);
        }
      }
      __syncthreads();   // protect slot-51 write from next-iter reads
    }
  }

  // ---- final flush: outb -> global (coalesced-ish, once) ----
  __syncthreads();
  for (int i = tid; i < TTOT * NB; i += THREADS) {
    int b = i / TTOT, t = i - b * TTOT;
    out[(size_t)(baseb + b) * TTOT + t] = outb[t][b];
  }
}

extern "C" void kernel_launch(void* const* d_in, const int* in_sizes, int n_in,
                              void* d_out, int out_size, void* d_ws, size_t ws_size,
                              hipStream_t stream) {
  (void)in_sizes; (void)n_in; (void)d_ws; (void)ws_size; (void)out_size;
  const float* inp  = (const float*)d_in[0];
  const float* Wih1 = (const float*)d_in[1];
  const float* bih1 = (const float*)d_in[2];
  const float* Whh1 = (const float*)d_in[3];
  const float* bhh1 = (const float*)d_in[4];
  const float* Wih2 = (const float*)d_in[5];
  const float* bih2 = (const float*)d_in[6];
  const float* Whh2 = (const float*)d_in[7];
  const float* bhh2 = (const float*)d_in[8];
  const float* Wlin = (const float*)d_in[9];
  const float* blin = (const float*)d_in[10];
  float* outp = (float*)d_out;

  lstm2_kernel<<<NBLOCKS, THREADS, 0, stream>>>(
      inp, Wih1, bih1, Whh1, bhh1, Wih2, bih2, Whh2, bhh2, Wlin, blin, outp);
}

// Round 10
// 232.614 us; speedup vs baseline: 1.5128x; 1.2405x over previous
//
#include <hip/hip_runtime.h>
#include <math.h>

#define H 51
#define TSEEN 256
#define FUT 16
#define TTOT (TSEEN + FUT)
#define NB 8
#define THREADS 512
#define NWAVE 8
#define UPW 7                 // units per wave (8*7=56 >= 51)
#define NBLOCKS (2048 / NB)   // 256 blocks -> 1/CU, 8 waves = 2 waves/SIMD

typedef _Float16 f16;
typedef _Float16 f16x8 __attribute__((ext_vector_type(8)));
typedef float f32x4 __attribute__((ext_vector_type(4)));

__device__ __forceinline__ float fast_rcp(float x) { return __builtin_amdgcn_rcpf(x); }
// sigmoid/tanh via v_exp; both saturate cleanly (rcp(inf)=0)
__device__ __forceinline__ float sigf(float x) {
  return fast_rcp(1.f + __expf(-x));
}
__device__ __forceinline__ float tanhf_(float x) {
  return fmaf(2.f, fast_rcp(1.f + __expf(-2.f * x)), -1.f);
}

// lane^8 within each 16-lane row: DPP row_ror:8 (VALU pipe, not LDS!)
__device__ __forceinline__ float xor8f(float v) {
  return __int_as_float(__builtin_amdgcn_mov_dpp(__float_as_int(v), 0x128, 0xf, 0xf, true));
}

#define MFMA __builtin_amdgcn_mfma_f32_16x16x32_f16

__launch_bounds__(THREADS, 2)
__global__ void lstm2_kernel(const float* __restrict__ inp,
                             const float* __restrict__ Wih1,
                             const float* __restrict__ bih1,
                             const float* __restrict__ Whh1,
                             const float* __restrict__ bhh1,
                             const float* __restrict__ Wih2,
                             const float* __restrict__ bih2,
                             const float* __restrict__ Whh2,
                             const float* __restrict__ bhh2,
                             const float* __restrict__ Wlin,
                             const float* __restrict__ blin,
                             float* __restrict__ out)
{
  // B-operand buffers in MFMA fragment layout, hi/lo packed in COLUMNS:
  // col b (0..7) = h_hi of batch b, col b+8 = h_lo of batch b.
  // [parity][ktile][lane][j]; logical (k,n): lane = n + 16*((k&31)>>3), j = k&7
  __shared__ __align__(16) f16 Bh1[2][2][64][8];
  __shared__ __align__(16) f16 Bh2[2][2][64][8];
  __shared__ __align__(16) float xs[TSEEN][NB];
  __shared__ float parts[2][NWAVE][NB];
  __shared__ float outb[TTOT][NB];   // staged outputs; flushed once at the end

  const int tid  = threadIdx.x;
  const int wv   = tid >> 6;
  const int lane = tid & 63;
  const int l15  = lane & 15;
  const int g4   = lane >> 4;
  const int bq   = l15 & 7;            // this lane's batch for the cell phase
  const bool mhi = (l15 & 8) != 0;     // takes the m=1 tile after xor8-sum
  const int baseb = blockIdx.x * NB;

  // ---- zero B buffers (pad slots stay 0 forever) ----
  {
    f16* b1 = &Bh1[0][0][0][0];
    f16* b2 = &Bh2[0][0][0][0];
    for (int i = tid; i < 2 * 2 * 64 * 8; i += THREADS) {
      b1[i] = (f16)0.f; b2[i] = (f16)0.f;
    }
  }
  // ---- stage inputs (coalesced per batch row) ----
  for (int i = tid; i < NB * TSEEN; i += THREADS) {
    int b = i >> 8, t = i & 255;
    xs[t][b] = inp[(size_t)(baseb + b) * TSEEN + t];
  }
  if (tid < 2 * NWAVE * NB) (&parts[0][0][0])[tid] = 0.f;

  // ---- A fragments (f16), virtual row v = 4*unit_slot + gate; 2 M-tiles/wave ----
  f16x8 A1[2][2], A2[2][2], A3[2][2];
  #pragma unroll
  for (int m = 0; m < 2; ++m) {
    const int slotA = 4 * m + (l15 >> 2);
    const int uA = UPW * wv + slotA;
    const int gA = l15 & 3;
    const bool vA = (slotA < UPW) && (uA < H);
    const int row = gA * H + (vA ? uA : 0);
    #pragma unroll
    for (int kt = 0; kt < 2; ++kt) {
      #pragma unroll
      for (int j = 0; j < 8; ++j) {
        const int k = 32 * kt + 8 * g4 + j;
        float w1 = 0.f, w2 = 0.f, w3 = 0.f;
        if (vA) {
          if (k < H) {
            w1 = Whh1[row * H + k];
            w2 = Wih2[row * H + k];
            w3 = Whh2[row * H + k];
          } else if (k == H) {
            w1 = Wih1[row];        // x folded in as k-slot 51 (layer 1 only)
          }
        }
        A1[m][kt][j] = (f16)w1;
        A2[m][kt][j] = (f16)w2;
        A3[m][kt][j] = (f16)w3;
      }
    }
  }

  // ---- bias C-in fragments (C layout: unit_slot = 4m+g4, gate = reg) ----
  // Seed bias ONLY in hi columns (l15 < 8); lo columns must accumulate from 0.
  f32x4 bias1[2], bias2[2];
  #pragma unroll
  for (int m = 0; m < 2; ++m) {
    const int ulC = 4 * m + g4;
    const int u = UPW * wv + ulC;
    const bool v = (ulC < UPW) && (u < H) && (l15 < 8);
    #pragma unroll
    for (int r = 0; r < 4; ++r) {
      const int rr = r * H + (v ? u : 0);
      bias1[m][r] = v ? (bih1[rr] + bhh1[rr]) : 0.f;
      bias2[m][r] = v ? (bih2[rr] + bhh2[rr]) : 0.f;
    }
  }

  // ---- this lane's cell: unit slot (mhi? 4:0)+g4, batch bq ----
  const int slotC = (mhi ? 4 : 0) + g4;
  const int uC0 = UPW * wv + slotC;
  const bool vC = (slotC < UPW) && (uC0 < H);
  const int uC = vC ? uC0 : 0;
  const float wl = vC ? Wlin[uC] : 0.f;
  const float bl = blin[0];
  const int wkt = uC >> 5;                    // h-frag write address for (uC,bq)
  const int wln = bq + 16 * ((uC >> 3) & 3);  // hi col; lo col = wln + 8
  const int wj  = uC & 7;

  float c1 = 0.f, c2 = 0.f;

  __syncthreads();
  // x(0) into stale-parity h1 buffer, k-slot 51 (kt=1 -> lane n+32, j=3)
  if (tid < NB) {
    float x0 = xs[0][tid];
    f16 xh = (f16)x0;
    Bh1[1][1][tid + 32][3] = xh;                    // hi col
    Bh1[1][1][tid + 40][3] = (f16)(x0 - (float)xh); // lo col (+8)
  }
  __syncthreads();

  #pragma unroll 1
  for (int t = 0; t < TTOT; ++t) {
    const int pw = t & 1, pr = pw ^ 1;

    // ============ phase 1: layer 1 only (reads Bh1[pr], incl. x at k=51) ============
    const f16x8 b1k0 = *(const f16x8*)&Bh1[pr][0][lane][0];
    const f16x8 b1k1 = *(const f16x8*)&Bh1[pr][1][lane][0];

    f32x4 ac1[2];
    #pragma unroll
    for (int m = 0; m < 2; ++m) {
      f32x4 c = MFMA(A1[m][0], b1k0, bias1[m], 0, 0, 0);
      ac1[m] = MFMA(A1[m][1], b1k1, c, 0, 0, 0);
    }

    // hi+lo recombine (xor8 partner holds the other half) + m-select
    float q0, q1, q2, q3;
    {
      float s00 = ac1[0][0] + xor8f(ac1[0][0]);
      float s01 = ac1[0][1] + xor8f(ac1[0][1]);
      float s02 = ac1[0][2] + xor8f(ac1[0][2]);
      float s03 = ac1[0][3] + xor8f(ac1[0][3]);
      float s10 = ac1[1][0] + xor8f(ac1[1][0]);
      float s11 = ac1[1][1] + xor8f(ac1[1][1]);
      float s12 = ac1[1][2] + xor8f(ac1[1][2]);
      float s13 = ac1[1][3] + xor8f(ac1[1][3]);
      q0 = mhi ? s10 : s00;
      q1 = mhi ? s11 : s01;
      q2 = mhi ? s12 : s02;
      q3 = mhi ? s13 : s03;
    }
    {
      float iv = sigf(q0), fv = sigf(q1);
      float gv = tanhf_(q2), ov = sigf(q3);
      c1 = fmaf(fv, c1, iv * gv);
      float h1n = ov * tanhf_(c1);
      if (vC) {
        f16 hh = (f16)h1n;
        Bh1[pw][wkt][wln][wj]     = hh;
        Bh1[pw][wkt][wln + 8][wj] = (f16)(h1n - (float)hh);
      }
    }
    // x(t+1) from input, written pre-barrier (slot 51 disjoint from h-slots;
    // phase-2 reads of slot 51 hit a zero column in A2)
    if (t + 1 < TSEEN && tid < NB) {
      float xn = xs[t + 1][tid];
      f16 xh = (f16)xn;
      Bh1[pw][1][tid + 32][3] = xh;
      Bh1[pw][1][tid + 40][3] = (f16)(xn - (float)xh);
    }
    __syncthreads();   // barrier A — the only per-step barrier (seen phase)

    // deferred output: out(t-1) for t-1 in [0, 254] -> LDS stage (no global store)
    if (t >= 1 && t < TSEEN && tid < NB) {
      float s = bl;
      #pragma unroll
      for (int w = 0; w < NWAVE; ++w) s += parts[pr][w][tid];
      outb[t - 1][tid] = s;
    }

    // ============ phase 2: layer 2 (hh from Bh2[pr], ih from fresh Bh1[pw]) ============
    const f16x8 b2k0 = *(const f16x8*)&Bh2[pr][0][lane][0];
    const f16x8 b2k1 = *(const f16x8*)&Bh2[pr][1][lane][0];
    const f16x8 f1k0 = *(const f16x8*)&Bh1[pw][0][lane][0];
    const f16x8 f1k1 = *(const f16x8*)&Bh1[pw][1][lane][0];

    f32x4 ac2[2];
    #pragma unroll
    for (int m = 0; m < 2; ++m) {
      f32x4 c = MFMA(A3[m][0], b2k0, bias2[m], 0, 0, 0);
      c = MFMA(A3[m][1], b2k1, c, 0, 0, 0);
      c = MFMA(A2[m][0], f1k0, c, 0, 0, 0);
      ac2[m] = MFMA(A2[m][1], f1k1, c, 0, 0, 0);
    }

    // recombine + m-select + cell + head
    {
      float s00 = ac2[0][0] + xor8f(ac2[0][0]);
      float s01 = ac2[0][1] + xor8f(ac2[0][1]);
      float s02 = ac2[0][2] + xor8f(ac2[0][2]);
      float s03 = ac2[0][3] + xor8f(ac2[0][3]);
      float s10 = ac2[1][0] + xor8f(ac2[1][0]);
      float s11 = ac2[1][1] + xor8f(ac2[1][1]);
      float s12 = ac2[1][2] + xor8f(ac2[1][2]);
      float s13 = ac2[1][3] + xor8f(ac2[1][3]);
      q0 = mhi ? s10 : s00;
      q1 = mhi ? s11 : s01;
      q2 = mhi ? s12 : s02;
      q3 = mhi ? s13 : s03;
    }
    float pv;
    {
      float iv = sigf(q0), fv = sigf(q1);
      float gv = tanhf_(q2), ov = sigf(q3);
      c2 = fmaf(fv, c2, iv * gv);
      float h2n = ov * tanhf_(c2);
      pv = wl * h2n;
      if (vC) {
        f16 hh = (f16)h2n;
        Bh2[pw][wkt][wln][wj]     = hh;
        Bh2[pw][wkt][wln + 8][wj] = (f16)(h2n - (float)hh);
      }
    }
    // butterfly over unit slots: xor8 via DPP (VALU), xor16/32 via bpermute
    pv += xor8f(pv);
    pv += __shfl_xor(pv, 16, 64);
    pv += __shfl_xor(pv, 32, 64);
    if (lane < NB) parts[pw][wv][lane] = pv;

    // feedback phase: x(t+1) = out(t); also emit outs 255..271
    if (t >= TSEEN - 1) {
      __syncthreads();   // publish parts[pw]
      if (tid < NB) {
        float fbv = bl;
        #pragma unroll
        for (int w = 0; w < NWAVE; ++w) fbv += parts[pw][w][tid];
        outb[t][tid] = fbv;
        if (t < TTOT - 1) {
          f16 xh = (f16)fbv;
          Bh1[pw][1][tid + 32][3] = xh;
          Bh1[pw][1][tid + 40][3] = (f16)(fbv - (float)xh);
        }
      }
      __syncthreads();   // protect slot-51 write from next-iter reads
    }
  }

  // ---- final flush: outb -> global (once) ----
  __syncthreads();
  for (int i = tid; i < TTOT * NB; i += THREADS) {
    int b = i / TTOT, t = i - b * TTOT;
    out[(size_t)(baseb + b) * TTOT + t] = outb[t][b];
  }
}

extern "C" void kernel_launch(void* const* d_in, const int* in_sizes, int n_in,
                              void* d_out, int out_size, void* d_ws, size_t ws_size,
                              hipStream_t stream) {
  (void)in_sizes; (void)n_in; (void)d_ws; (void)ws_size; (void)out_size;
  const float* inp  = (const float*)d_in[0];
  const float* Wih1 = (const float*)d_in[1];
  const float* bih1 = (const float*)d_in[2];
  const float* Whh1 = (const float*)d_in[3];
  const float* bhh1 = (const float*)d_in[4];
  const float* Wih2 = (const float*)d_in[5];
  const float* bih2 = (const float*)d_in[6];
  const float* Whh2 = (const float*)d_in[7];
  const float* bhh2 = (const float*)d_in[8];
  const float* Wlin = (const float*)d_in[9];
  const float* blin = (const float*)d_in[10];
  float* outp = (float*)d_out;

  lstm2_kernel<<<NBLOCKS, THREADS, 0, stream>>>(
      inp, Wih1, bih1, Whh1, bhh1, Wih2, bih2, Whh2, bhh2, Wlin, blin, outp);
}

// Round 11
// 231.015 us; speedup vs baseline: 1.5233x; 1.0069x over previous
//
#include <hip/hip_runtime.h>
#include <math.h>

#define H 51
#define TSEEN 256
#define FUT 16
#define TTOT (TSEEN + FUT)
#define NB 8
#define THREADS 512
#define NWAVE 8
#define UPW 7                 // units per wave (8*7=56 >= 51)
#define NBLOCKS (2048 / NB)   // 256 blocks -> 1/CU, 8 waves = 2 waves/SIMD

typedef _Float16 f16;
typedef _Float16 f16x8 __attribute__((ext_vector_type(8)));
typedef float f32x4 __attribute__((ext_vector_type(4)));

__device__ __forceinline__ float fast_rcp(float x) { return __builtin_amdgcn_rcpf(x); }
// sigmoid/tanh via v_exp; both saturate cleanly (rcp(inf)=0)
__device__ __forceinline__ float sigf(float x) {
  return fast_rcp(1.f + __expf(-x));
}
__device__ __forceinline__ float tanhf_(float x) {
  return fmaf(2.f, fast_rcp(1.f + __expf(-2.f * x)), -1.f);
}

// lane^8 within each 16-lane row: DPP row_ror:8 (VALU pipe, not LDS!)
__device__ __forceinline__ float xor8f(float v) {
  return __int_as_float(__builtin_amdgcn_mov_dpp(__float_as_int(v), 0x128, 0xf, 0xf, true));
}

#define MFMA __builtin_amdgcn_mfma_f32_16x16x32_f16

// hi+lo recombine in send/keep form: lane b keeps tile0-hi, receives tile0-lo
// from lane b+8; lane b+8 keeps tile1-lo, receives tile1-hi from lane b.
__device__ __forceinline__ void recomb(const f32x4& a0, const f32x4& a1, bool mhi,
                                       float& q0, float& q1, float& q2, float& q3) {
  float s0 = mhi ? a0[0] : a1[0];
  float s1 = mhi ? a0[1] : a1[1];
  float s2 = mhi ? a0[2] : a1[2];
  float s3 = mhi ? a0[3] : a1[3];
  float k0 = mhi ? a1[0] : a0[0];
  float k1 = mhi ? a1[1] : a0[1];
  float k2 = mhi ? a1[2] : a0[2];
  float k3 = mhi ? a1[3] : a0[3];
  q0 = k0 + xor8f(s0);
  q1 = k1 + xor8f(s1);
  q2 = k2 + xor8f(s2);
  q3 = k3 + xor8f(s3);
}

__launch_bounds__(THREADS, 2)
__global__ void lstm2_kernel(const float* __restrict__ inp,
                             const float* __restrict__ Wih1,
                             const float* __restrict__ bih1,
                             const float* __restrict__ Whh1,
                             const float* __restrict__ bhh1,
                             const float* __restrict__ Wih2,
                             const float* __restrict__ bih2,
                             const float* __restrict__ Whh2,
                             const float* __restrict__ bhh2,
                             const float* __restrict__ Wlin,
                             const float* __restrict__ blin,
                             float* __restrict__ out)
{
  // B-operand buffers in MFMA fragment layout, hi/lo packed in COLUMNS:
  // col b (0..7) = h_hi of batch b, col b+8 = h_lo of batch b.
  // [parity][ktile][lane][j]; logical (k,n): lane = n + 16*((k&31)>>3), j = k&7
  __shared__ __align__(16) f16 Bh1[2][2][64][8];
  __shared__ __align__(16) f16 Bh2[2][2][64][8];
  __shared__ __align__(16) float xs[TSEEN][NB];
  __shared__ float parts[2][NWAVE][NB];
  __shared__ float outb[TTOT][NB];   // staged outputs; flushed once at the end

  const int tid  = threadIdx.x;
  const int wv   = tid >> 6;
  const int lane = tid & 63;
  const int l15  = lane & 15;
  const int g4   = lane >> 4;
  const int bq   = l15 & 7;            // this lane's batch for the cell phase
  const bool mhi = (l15 & 8) != 0;     // takes the m=1 tile after recombine
  const int baseb = blockIdx.x * NB;

  // ---- zero B buffers (pad slots stay 0 forever) ----
  {
    f16* b1 = &Bh1[0][0][0][0];
    f16* b2 = &Bh2[0][0][0][0];
    for (int i = tid; i < 2 * 2 * 64 * 8; i += THREADS) {
      b1[i] = (f16)0.f; b2[i] = (f16)0.f;
    }
  }
  // ---- stage inputs (coalesced per batch row) ----
  for (int i = tid; i < NB * TSEEN; i += THREADS) {
    int b = i >> 8, t = i & 255;
    xs[t][b] = inp[(size_t)(baseb + b) * TSEEN + t];
  }
  if (tid < 2 * NWAVE * NB) (&parts[0][0][0])[tid] = 0.f;

  // ---- A fragments (f16), virtual row v = 4*unit_slot + gate; 2 M-tiles/wave ----
  f16x8 A1[2][2], A2[2][2], A3[2][2];
  #pragma unroll
  for (int m = 0; m < 2; ++m) {
    const int slotA = 4 * m + (l15 >> 2);
    const int uA = UPW * wv + slotA;
    const int gA = l15 & 3;
    const bool vA = (slotA < UPW) && (uA < H);
    const int row = gA * H + (vA ? uA : 0);
    #pragma unroll
    for (int kt = 0; kt < 2; ++kt) {
      #pragma unroll
      for (int j = 0; j < 8; ++j) {
        const int k = 32 * kt + 8 * g4 + j;
        float w1 = 0.f, w2 = 0.f, w3 = 0.f;
        if (vA) {
          if (k < H) {
            w1 = Whh1[row * H + k];
            w2 = Wih2[row * H + k];
            w3 = Whh2[row * H + k];
          } else if (k == H) {
            w1 = Wih1[row];        // x folded in as k-slot 51 (layer 1 only)
          }
        }
        A1[m][kt][j] = (f16)w1;
        A2[m][kt][j] = (f16)w2;
        A3[m][kt][j] = (f16)w3;
      }
    }
  }

  // ---- bias C-in fragments (C layout: unit_slot = 4m+g4, gate = reg) ----
  // Seed bias ONLY in hi columns (l15 < 8); lo columns accumulate from 0.
  f32x4 bias1[2], bias2[2];
  #pragma unroll
  for (int m = 0; m < 2; ++m) {
    const int ulC = 4 * m + g4;
    const int u = UPW * wv + ulC;
    const bool v = (ulC < UPW) && (u < H) && (l15 < 8);
    #pragma unroll
    for (int r = 0; r < 4; ++r) {
      const int rr = r * H + (v ? u : 0);
      bias1[m][r] = v ? (bih1[rr] + bhh1[rr]) : 0.f;
      bias2[m][r] = v ? (bih2[rr] + bhh2[rr]) : 0.f;
    }
  }

  // ---- this lane's cell: unit slot (mhi? 4:0)+g4, batch bq ----
  const int slotC = (mhi ? 4 : 0) + g4;
  const int uC0 = UPW * wv + slotC;
  const bool vC = (slotC < UPW) && (uC0 < H);
  const int uC = vC ? uC0 : 0;
  const float wl = vC ? Wlin[uC] : 0.f;
  const float bl = blin[0];
  const int wkt = uC >> 5;                    // h-frag write address for (uC,bq)
  const int wln = bq + 16 * ((uC >> 3) & 3);  // hi col; lo col = wln + 8
  const int wj  = uC & 7;

  float c1 = 0.f, c2 = 0.f;
  const f32x4 zf = {0.f, 0.f, 0.f, 0.f};

  __syncthreads();
  // x(0) into stale-parity h1 buffer, k-slot 51 (kt=1 -> lane n+32, j=3)
  if (tid < NB) {
    float x0 = xs[0][tid];
    f16 xh = (f16)x0;
    Bh1[1][1][tid + 32][3] = xh;                    // hi col
    Bh1[1][1][tid + 40][3] = (f16)(x0 - (float)xh); // lo col (+8)
  }
  __syncthreads();

  // ---- prologue: prefetch G1(0) from Bh1[pr=1] (h=0, x(0) at slot 51) ----
  f32x4 ac1[2];
  {
    const f16x8 p0 = *(const f16x8*)&Bh1[1][0][lane][0];
    const f16x8 p1 = *(const f16x8*)&Bh1[1][1][lane][0];
    #pragma unroll
    for (int m = 0; m < 2; ++m) {
      f32x4 c = MFMA(A1[m][0], p0, bias1[m], 0, 0, 0);
      ac1[m] = MFMA(A1[m][1], p1, c, 0, 0, 0);
    }
  }

  #pragma unroll 1
  for (int t = 0; t < TTOT; ++t) {
    const int pw = t & 1, pr = pw ^ 1;

    // ============ phase 1 (pure VALU): C1(t) from prefetched ac1 ============
    float q0, q1, q2, q3;
    recomb(ac1[0], ac1[1], mhi, q0, q1, q2, q3);
    {
      float iv = sigf(q0), fv = sigf(q1);
      float gv = tanhf_(q2), ov = sigf(q3);
      c1 = fmaf(fv, c1, iv * gv);
      float h1n = ov * tanhf_(c1);
      if (vC) {
        f16 hh = (f16)h1n;
        Bh1[pw][wkt][wln][wj]     = hh;
        Bh1[pw][wkt][wln + 8][wj] = (f16)(h1n - (float)hh);
      }
    }
    // x(t+1) from input, written pre-barrier (slot 51 disjoint from h-slots)
    if (t + 1 < TSEEN && tid < NB) {
      float xn = xs[t + 1][tid];
      f16 xh = (f16)xn;
      Bh1[pw][1][tid + 32][3] = xh;
      Bh1[pw][1][tid + 40][3] = (f16)(xn - (float)xh);
    }
    __syncthreads();   // barrier A — the only per-step barrier (seen phase)

    // deferred output: out(t-1) for t-1 in [0, 254] -> LDS stage
    if (t >= 1 && t < TSEEN && tid < NB) {
      float s = bl;
      #pragma unroll
      for (int w = 0; w < NWAVE; ++w) s += parts[pr][w][tid];
      outb[t - 1][tid] = s;
    }

    // ==== phase 2: G2(t) (hh + ih) AND prefetch G1(t+1) on shared frags ====
    const f16x8 b2k0 = *(const f16x8*)&Bh2[pr][0][lane][0];
    const f16x8 b2k1 = *(const f16x8*)&Bh2[pr][1][lane][0];
    const f16x8 f1k0 = *(const f16x8*)&Bh1[pw][0][lane][0];
    const f16x8 f1k1 = *(const f16x8*)&Bh1[pw][1][lane][0];

    f32x4 ac2[2];
    #pragma unroll
    for (int m = 0; m < 2; ++m) {
      f32x4 r1 = MFMA(A3[m][0], b2k0, bias2[m], 0, 0, 0);
      r1 = MFMA(A3[m][1], b2k1, r1, 0, 0, 0);
      f32x4 r2 = MFMA(A2[m][0], f1k0, zf, 0, 0, 0);
      r2 = MFMA(A2[m][1], f1k1, r2, 0, 0, 0);
      ac2[m] = r1 + r2;
      // G1(t+1) prefetch: same B fragments, layer-1 A (x col live at slot 51)
      f32x4 n = MFMA(A1[m][0], f1k0, bias1[m], 0, 0, 0);
      ac1[m] = MFMA(A1[m][1], f1k1, n, 0, 0, 0);
    }

    // recombine + cell + head
    recomb(ac2[0], ac2[1], mhi, q0, q1, q2, q3);
    float pv;
    {
      float iv = sigf(q0), fv = sigf(q1);
      float gv = tanhf_(q2), ov = sigf(q3);
      c2 = fmaf(fv, c2, iv * gv);
      float h2n = ov * tanhf_(c2);
      pv = wl * h2n;
      if (vC) {
        f16 hh = (f16)h2n;
        Bh2[pw][wkt][wln][wj]     = hh;
        Bh2[pw][wkt][wln + 8][wj] = (f16)(h2n - (float)hh);
      }
    }
    // butterfly over unit slots: xor8 via DPP (VALU), xor16/32 via bpermute
    pv += xor8f(pv);
    pv += __shfl_xor(pv, 16, 64);
    pv += __shfl_xor(pv, 32, 64);
    if (lane < NB) parts[pw][wv][lane] = pv;

    // feedback phase: x(t+1) = out(t); redo G1(t+1) prefetch with fresh x
    if (t >= TSEEN - 1) {
      __syncthreads();   // publish parts[pw]
      if (tid < NB) {
        float fbv = bl;
        #pragma unroll
        for (int w = 0; w < NWAVE; ++w) fbv += parts[pw][w][tid];
        outb[t][tid] = fbv;
        if (t < TTOT - 1) {
          f16 xh = (f16)fbv;
          Bh1[pw][1][tid + 32][3] = xh;
          Bh1[pw][1][tid + 40][3] = (f16)(fbv - (float)xh);
        }
      }
      __syncthreads();   // slot-51 visible to all
      if (t < TTOT - 1) {
        const f16x8 g0 = *(const f16x8*)&Bh1[pw][0][lane][0];
        const f16x8 g1 = *(const f16x8*)&Bh1[pw][1][lane][0];
        #pragma unroll
        for (int m = 0; m < 2; ++m) {
          f32x4 c = MFMA(A1[m][0], g0, bias1[m], 0, 0, 0);
          ac1[m] = MFMA(A1[m][1], g1, c, 0, 0, 0);
        }
      }
    }
  }

  // ---- final flush: outb -> global (once) ----
  __syncthreads();
  for (int i = tid; i < TTOT * NB; i += THREADS) {
    int b = i / TTOT, t = i - b * TTOT;
    out[(size_t)(baseb + b) * TTOT + t] = outb[t][b];
  }
}

extern "C" void kernel_launch(void* const* d_in, const int* in_sizes, int n_in,
                              void* d_out, int out_size, void* d_ws, size_t ws_size,
                              hipStream_t stream) {
  (void)in_sizes; (void)n_in; (void)d_ws; (void)ws_size; (void)out_size;
  const float* inp  = (const float*)d_in[0];
  const float* Wih1 = (const float*)d_in[1];
  const float* bih1 = (const float*)d_in[2];
  const float* Whh1 = (const float*)d_in[3];
  const float* bhh1 = (const float*)d_in[4];
  const float* Wih2 = (const float*)d_in[5];
  const float* bih2 = (const float*)d_in[6];
  const float* Whh2 = (const float*)d_in[7];
  const float* bhh2 = (const float*)d_in[8];
  const float* Wlin = (const float*)d_in[9];
  const float* blin = (const float*)d_in[10];
  float* outp = (float*)d_out;

  lstm2_kernel<<<NBLOCKS, THREADS, 0, stream>>>(
      inp, Wih1, bih1, Whh1, bhh1, Wih2, bih2, Whh2, bhh2, Wlin, blin, outp);
}